// Round 3
// baseline (142.877 us; speedup 1.0000x reference)
//
#include <hip/hip_runtime.h>
#include <hip/hip_bf16.h>

// Problem constants
#define B_   8
#define L_   128
#define S_   160
#define H_   768
#define T_   16
#define CD_  50
#define WD_  100
#define NGATE 200   // 4*CD
#define NEGV (-1e30f)

#define G_ELEMS ((size_t)2048 * T_ * NGATE)          // 6.55M floats = 26.2 MB
#define WS_NEED (256 + G_ELEMS * 4)

// ---- float <-> monotonic unsigned encoding (for atomic min on floats) ----
__device__ __forceinline__ unsigned fenc(float f) {
    unsigned b = __float_as_uint(f);
    return (b & 0x80000000u) ? ~b : (b | 0x80000000u);
}
__device__ __forceinline__ float fdec(unsigned u) {
    return __uint_as_float((u & 0x80000000u) ? (u ^ 0x80000000u) : ~u);
}

__device__ __forceinline__ float sigm(float x) {
    return __fdividef(1.f, 1.f + __expf(-x));
}
__device__ __forceinline__ float tanh_fast(float x) {
    float a = fabsf(x);
    float e = __expf(-2.f * a);
    float t = __fdividef(1.f - e, 1.f + e);
    return copysignf(t, x);
}

// ---------------- Kernel 1: global min of bert_emb ----------------
__global__ __launch_bounds__(256) void kmin(const float* __restrict__ x, unsigned* __restrict__ wsmin) {
    int i = blockIdx.x * 256 + threadIdx.x;
    const float4* x4 = (const float4*)x;
    float4 v = x4[i];
    float m = fminf(fminf(v.x, v.y), fminf(v.z, v.w));
    __shared__ float red[256];
    red[threadIdx.x] = m;
    __syncthreads();
    for (int o = 128; o > 0; o >>= 1) {
        if (threadIdx.x < o) red[threadIdx.x] = fminf(red[threadIdx.x], red[threadIdx.x + o]);
        __syncthreads();
    }
    if (threadIdx.x == 0) atomicMin(wsmin, fenc(red[0]));
}

// ---------------- Kernel 2: word_reps maxpool (4 words/block) + word_embed + cls ----------------
__global__ __launch_bounds__(256) void kword4(const float* __restrict__ bert, const int* __restrict__ p2w,
                                              const int* __restrict__ word_ids, const float* __restrict__ word_table,
                                              const unsigned* __restrict__ wsmin, float* __restrict__ out) {
    int blk = blockIdx.x;            // 256 blocks: b = blk>>5, l0 = (blk&31)*4
    int b = blk >> 5;
    int l0 = (blk & 31) << 2;
    int tid = threadIdx.x;

    __shared__ int mask[4][S_];
    for (int idx = tid; idx < 4 * S_; idx += 256) {
        int li = idx / S_, s = idx % S_;
        mask[li][s] = p2w[((size_t)(b * L_ + l0 + li)) * S_ + s];
    }
    __syncthreads();

    float minv = fdec(wsmin[0]);
    float a[4][3];
#pragma unroll
    for (int li = 0; li < 4; ++li) { a[li][0] = minv; a[li][1] = minv; a[li][2] = minv; }

    const float* bb = bert + (size_t)b * S_ * H_ + tid;
#pragma unroll 4
    for (int s = 0; s < S_; ++s) {
        float v0 = bb[(size_t)s * H_];
        float v1 = bb[(size_t)s * H_ + 256];
        float v2 = bb[(size_t)s * H_ + 512];
#pragma unroll
        for (int li = 0; li < 4; ++li) {
            if (mask[li][s]) {
                a[li][0] = fmaxf(a[li][0], v0);
                a[li][1] = fmaxf(a[li][1], v1);
                a[li][2] = fmaxf(a[li][2], v2);
            }
        }
    }
#pragma unroll
    for (int li = 0; li < 4; ++li) {
        float* orow = out + (size_t)(b * L_ + l0 + li) * 968;
        orow[tid] = a[li][0]; orow[tid + 256] = a[li][1]; orow[tid + 512] = a[li][2];
    }
    if (tid < WD_) {
#pragma unroll
        for (int li = 0; li < 4; ++li) {
            int wid = word_ids[b * L_ + l0 + li];
            out[(size_t)(b * L_ + l0 + li) * 968 + 768 + tid] = word_table[(size_t)wid * WD_ + tid];
        }
    }
    if ((blk & 31) == 0) {   // cls embedding = bert_emb[b,0,:]
        const float* c = bert + (size_t)b * S_ * H_;
        float* co = out + (size_t)B_ * L_ * 968 + (size_t)b * H_;
        co[tid] = c[tid]; co[tid + 256] = c[tid + 256]; co[tid + 512] = c[tid + 512];
    }
}

// ---- weight row -> 13 named float4 registers (rows are only 8B-aligned -> float2 loads) ----
#define LDW(W, p) { float2 a_ = *(const float2*)(p); float2 b_ = *(const float2*)((p) + 2); \
                    W = make_float4(a_.x, a_.y, b_.x, b_.y); }

// ---------------- Kernel 3a: x-part gates, G[n][t][j] = w_ih[j].x[n][t] + b[j] ----------------
// grid = 2048 (n = dir*1024 + seq), 256 threads (200 active in compute)
__global__ __launch_bounds__(256) void kxg(const int* __restrict__ char_ids, const int* __restrict__ char_count,
                                           const float* __restrict__ char_table,
                                           const float* __restrict__ w_ih_f, const float* __restrict__ b_f,
                                           const float* __restrict__ w_ih_b, const float* __restrict__ b_b,
                                           float* __restrict__ G) {
    int n = blockIdx.x;
    int dir = n >> 10;
    int seq = n & 1023;
    int tid = threadIdx.x;

    __shared__ int cid[T_];
    __shared__ int len_s;
    __shared__ __align__(16) float xs[T_][52];   // padded to 52 for float4 reads; pad zeroed

    if (tid < T_) cid[tid] = char_ids[seq * T_ + tid];
    if (tid == 0) { int c = char_count[seq]; len_s = (c > 0) ? c : 1; }
    __syncthreads();
    int len = len_s;
    for (int idx = tid; idx < T_ * 52; idx += 256) {
        int t = idx / 52, k = idx % 52;
        int st = dir ? (len - 1 - t) : t;
        float xv = 0.f;
        if (k < CD_ && st >= 0) xv = char_table[cid[st] * CD_ + k];
        xs[t][k] = xv;
    }

    float4 wq0, wq1, wq2, wq3, wq4, wq5, wq6, wq7, wq8, wq9, wq10, wq11, wq12;
    float bj = 0.f;
    if (tid < NGATE) {
        const float* wrow = (dir ? w_ih_b : w_ih_f) + tid * CD_;
        LDW(wq0,  wrow +  0) LDW(wq1,  wrow +  4) LDW(wq2,  wrow +  8) LDW(wq3,  wrow + 12)
        LDW(wq4,  wrow + 16) LDW(wq5,  wrow + 20) LDW(wq6,  wrow + 24) LDW(wq7,  wrow + 28)
        LDW(wq8,  wrow + 32) LDW(wq9,  wrow + 36) LDW(wq10, wrow + 40) LDW(wq11, wrow + 44)
        { float2 a_ = *(const float2*)(wrow + 48); wq12 = make_float4(a_.x, a_.y, 0.f, 0.f); }
        bj = (dir ? b_b : b_f)[tid];
    }
    __syncthreads();

#define KXG4(i) { \
    float4 xa = *(const float4*)(x0 + 4 * i); \
    float4 xb = *(const float4*)(x1 + 4 * i); \
    accA = fmaf(wq##i.x, xa.x, accA); accA = fmaf(wq##i.y, xa.y, accA); \
    accA = fmaf(wq##i.z, xa.z, accA); accA = fmaf(wq##i.w, xa.w, accA); \
    accB = fmaf(wq##i.x, xb.x, accB); accB = fmaf(wq##i.y, xb.y, accB); \
    accB = fmaf(wq##i.z, xb.z, accB); accB = fmaf(wq##i.w, xb.w, accB); }

    if (tid < NGATE) {
        float* gout = G + (size_t)n * T_ * NGATE + tid;
#pragma unroll
        for (int t2 = 0; t2 < T_; t2 += 2) {
            const float* x0 = &xs[t2][0];
            const float* x1 = &xs[t2 + 1][0];
            float accA = bj, accB = bj;
            KXG4(0) KXG4(1) KXG4(2) KXG4(3) KXG4(4) KXG4(5) KXG4(6)
            KXG4(7) KXG4(8) KXG4(9) KXG4(10) KXG4(11) KXG4(12)
            gout[t2 * NGATE] = accA;
            gout[(t2 + 1) * NGATE] = accB;
        }
    }
}

// ---------------- Kernel 3b: recurrent h-part + fused masked max-pool ----------------
// grid = 512: dir = blk>>8, grp = blk&255 covers 4 seqs. W_hh row in 13 named float4s.
__global__ __launch_bounds__(256) void krec(const float* __restrict__ G, const int* __restrict__ char_count,
                                            const int* __restrict__ tok_mask,
                                            const float* __restrict__ w_hh_f, const float* __restrict__ w_hh_b,
                                            float* __restrict__ out) {
    int dir = blockIdx.x >> 8;
    int grp = blockIdx.x & 255;
    int tid = threadIdx.x;

    __shared__ __align__(16) float hbuf[52][4];   // [k][s], rows 50/51 stay zero
    __shared__ float gbuf[4][NGATE];
    __shared__ int slen[4], smask[4];

    if (tid < 4) {
        int n = grp * 4 + tid;
        int c = char_count[n];
        slen[tid] = (c > 0) ? c : 1;
        int mb = 0;
        for (int t = 0; t < T_; ++t) mb |= (tok_mask[n * T_ + t] != 0) << t;
        smask[tid] = mb;
    }
    for (int idx = tid; idx < 52 * 4; idx += 256) ((float*)hbuf)[idx] = 0.f;

    float4 wq0, wq1, wq2, wq3, wq4, wq5, wq6, wq7, wq8, wq9, wq10, wq11, wq12;
    float gx0 = 0.f, gx1 = 0.f, gx2 = 0.f, gx3 = 0.f;
    const float* Gb = G + (size_t)(dir * 1024 + grp * 4) * T_ * NGATE + tid;
    if (tid < NGATE) {
        const float* wrow = (dir ? w_hh_b : w_hh_f) + tid * CD_;
        LDW(wq0,  wrow +  0) LDW(wq1,  wrow +  4) LDW(wq2,  wrow +  8) LDW(wq3,  wrow + 12)
        LDW(wq4,  wrow + 16) LDW(wq5,  wrow + 20) LDW(wq6,  wrow + 24) LDW(wq7,  wrow + 28)
        LDW(wq8,  wrow + 32) LDW(wq9,  wrow + 36) LDW(wq10, wrow + 40) LDW(wq11, wrow + 44)
        { float2 a_ = *(const float2*)(wrow + 48); wq12 = make_float4(a_.x, a_.y, 0.f, 0.f); }
        gx0 = Gb[0];
        gx1 = Gb[1 * T_ * NGATE];
        gx2 = Gb[2 * T_ * NGATE];
        gx3 = Gb[3 * T_ * NGATE];
    }
    __syncthreads();

    int cell = tid % CD_;
    int sb = tid / CD_;          // 0..3
    float creg = 0.f, mreg = NEGV;

#define KREC4(i) { \
    float4 h0 = *(const float4*)&hbuf[4 * i][0]; \
    float4 h1 = *(const float4*)&hbuf[4 * i + 1][0]; \
    float4 h2 = *(const float4*)&hbuf[4 * i + 2][0]; \
    float4 h3 = *(const float4*)&hbuf[4 * i + 3][0]; \
    acc0 = fmaf(wq##i.x, h0.x, acc0); acc1 = fmaf(wq##i.x, h0.y, acc1); \
    acc2 = fmaf(wq##i.x, h0.z, acc2); acc3 = fmaf(wq##i.x, h0.w, acc3); \
    acc0 = fmaf(wq##i.y, h1.x, acc0); acc1 = fmaf(wq##i.y, h1.y, acc1); \
    acc2 = fmaf(wq##i.y, h1.z, acc2); acc3 = fmaf(wq##i.y, h1.w, acc3); \
    acc0 = fmaf(wq##i.z, h2.x, acc0); acc1 = fmaf(wq##i.z, h2.y, acc1); \
    acc2 = fmaf(wq##i.z, h2.z, acc2); acc3 = fmaf(wq##i.z, h2.w, acc3); \
    acc0 = fmaf(wq##i.w, h3.x, acc0); acc1 = fmaf(wq##i.w, h3.y, acc1); \
    acc2 = fmaf(wq##i.w, h3.z, acc2); acc3 = fmaf(wq##i.w, h3.w, acc3); }

#pragma unroll 1
    for (int t = 0; t < T_; ++t) {
        float gn0, gn1, gn2, gn3;
        if (tid < NGATE) {
            if (t < T_ - 1) {          // prefetch next step's x-gates (hidden under h-dot)
                const float* Gn = Gb + (t + 1) * NGATE;
                gn0 = Gn[0];
                gn1 = Gn[1 * T_ * NGATE];
                gn2 = Gn[2 * T_ * NGATE];
                gn3 = Gn[3 * T_ * NGATE];
            }
            float acc0 = gx0, acc1 = gx1, acc2 = gx2, acc3 = gx3;
            KREC4(0) KREC4(1) KREC4(2) KREC4(3) KREC4(4) KREC4(5) KREC4(6)
            KREC4(7) KREC4(8) KREC4(9) KREC4(10) KREC4(11) KREC4(12)
            gbuf[0][tid] = acc0; gbuf[1][tid] = acc1; gbuf[2][tid] = acc2; gbuf[3][tid] = acc3;
        }
        __syncthreads();
        if (tid < NGATE) {
            float gi = gbuf[sb][cell];
            float gf = gbuf[sb][cell + CD_];
            float gg = gbuf[sb][cell + 2 * CD_];
            float go = gbuf[sb][cell + 3 * CD_];
            float cc = sigm(gf) * creg + sigm(gi) * tanh_fast(gg);
            float h = sigm(go) * tanh_fast(cc);
            creg = cc;
            hbuf[cell][sb] = h;
            int tt = dir ? (slen[sb] - 1 - t) : t;
            if (tt >= 0 && ((smask[sb] >> tt) & 1)) mreg = fmaxf(mreg, h);
            if (t < T_ - 1) { gx0 = gn0; gx1 = gn1; gx2 = gn2; gx3 = gn3; }
        }
        __syncthreads();
    }

    if (tid < NGATE) {
        float m = mreg;
        if (dir && (smask[sb] >> slen[sb])) m = fmaxf(m, 0.f);   // masked t>=len contribute 0 in bwd half
        if (m == NEGV) m = 0.f;
        out[(size_t)(grp * 4 + sb) * 968 + 868 + dir * CD_ + cell] = m;
    }
}

// ---------------- Fallback (R2 klstm) if workspace can't hold G ----------------
#define NSEQ 8
__global__ __launch_bounds__(256, 1) void klstm(const int* __restrict__ char_ids, const int* __restrict__ char_count,
                                                const int* __restrict__ tok_mask, const float* __restrict__ char_table,
                                                const float* __restrict__ w_ih_f, const float* __restrict__ w_hh_f,
                                                const float* __restrict__ b_f,
                                                const float* __restrict__ w_ih_b, const float* __restrict__ w_hh_b,
                                                const float* __restrict__ b_b,
                                                float* __restrict__ out) {
    int dir = blockIdx.x & 1;
    int grp = blockIdx.x >> 1;
    int tid = threadIdx.x;

    __shared__ __align__(16) float xall[T_][CD_][NSEQ];
    __shared__ __align__(16) float hbuf[CD_][NSEQ];
    __shared__ __align__(16) float gbuf[NSEQ][NGATE];
    __shared__ int cid[NSEQ][T_];
    __shared__ int slen[NSEQ];
    __shared__ int smask[NSEQ];

    for (int idx = tid; idx < NSEQ * T_; idx += 256) {
        int s = idx >> 4, t = idx & 15;
        cid[s][t] = char_ids[(grp * NSEQ + s) * T_ + t];
    }
    if (tid < NSEQ) {
        int n = grp * NSEQ + tid;
        int c = char_count[n];
        slen[tid] = (c > 0) ? c : 1;
        int mb = 0;
        for (int t = 0; t < T_; ++t) mb |= (tok_mask[n * T_ + t] != 0) << t;
        smask[tid] = mb;
    }
    __syncthreads();
    for (int idx = tid; idx < T_ * CD_ * NSEQ; idx += 256) {
        int s = idx & 7;
        int k = (idx >> 3) % CD_;
        int t = idx / (CD_ * NSEQ);
        int st = dir ? (slen[s] - 1 - t) : t;
        float xv = 0.f;
        if (st >= 0) xv = char_table[cid[s][st] * CD_ + k];
        xall[t][k][s] = xv;
    }
    for (int idx = tid; idx < CD_ * NSEQ; idx += 256) hbuf[idx >> 3][idx & 7] = 0.f;

    float wihr[CD_], whhr[CD_];
    float bj = 0.f;
    if (tid < NGATE) {
        const float* wih = dir ? w_ih_b : w_ih_f;
        const float* whh = dir ? w_hh_b : w_hh_f;
#pragma unroll
        for (int k2 = 0; k2 < CD_ / 2; ++k2) {
            float2 a = *(const float2*)(wih + tid * CD_ + 2 * k2);
            wihr[2 * k2] = a.x; wihr[2 * k2 + 1] = a.y;
            float2 b2 = *(const float2*)(whh + tid * CD_ + 2 * k2);
            whhr[2 * k2] = b2.x; whhr[2 * k2 + 1] = b2.y;
        }
        bj = (dir ? b_b : b_f)[tid];
    }
    __syncthreads();

    int cell = tid % CD_;
    int sb = tid / CD_;
    float creg[2] = {0.f, 0.f};
    float mreg[2] = {NEGV, NEGV};

#pragma unroll 1
    for (int t = 0; t < T_; ++t) {
        if (tid < NGATE) {
            float acc[NSEQ];
#pragma unroll
            for (int s = 0; s < NSEQ; ++s) acc[s] = bj;
            const float* xk = &xall[t][0][0];
#pragma unroll
            for (int k = 0; k < CD_; ++k) {
                float4 xa = *(const float4*)(xk + k * NSEQ);
                float4 xb = *(const float4*)(xk + k * NSEQ + 4);
                float w = wihr[k];
                acc[0] = fmaf(w, xa.x, acc[0]); acc[1] = fmaf(w, xa.y, acc[1]);
                acc[2] = fmaf(w, xa.z, acc[2]); acc[3] = fmaf(w, xa.w, acc[3]);
                acc[4] = fmaf(w, xb.x, acc[4]); acc[5] = fmaf(w, xb.y, acc[5]);
                acc[6] = fmaf(w, xb.z, acc[6]); acc[7] = fmaf(w, xb.w, acc[7]);
            }
#pragma unroll
            for (int k = 0; k < CD_; ++k) {
                float4 ha = *(const float4*)(&hbuf[k][0]);
                float4 hb = *(const float4*)(&hbuf[k][4]);
                float w = whhr[k];
                acc[0] = fmaf(w, ha.x, acc[0]); acc[1] = fmaf(w, ha.y, acc[1]);
                acc[2] = fmaf(w, ha.z, acc[2]); acc[3] = fmaf(w, ha.w, acc[3]);
                acc[4] = fmaf(w, hb.x, acc[4]); acc[5] = fmaf(w, hb.y, acc[5]);
                acc[6] = fmaf(w, hb.z, acc[6]); acc[7] = fmaf(w, hb.w, acc[7]);
            }
#pragma unroll
            for (int s = 0; s < NSEQ; ++s) gbuf[s][tid] = acc[s];
        }
        __syncthreads();
        if (tid < NGATE) {
#pragma unroll
            for (int p = 0; p < 2; ++p) {
                int s = sb + 4 * p;
                float gi = gbuf[s][cell];
                float gf = gbuf[s][cell + CD_];
                float gg = gbuf[s][cell + 2 * CD_];
                float go = gbuf[s][cell + 3 * CD_];
                float cc = creg[p];
                cc = sigm(gf) * cc + sigm(gi) * tanh_fast(gg);
                float h = sigm(go) * tanh_fast(cc);
                creg[p] = cc;
                hbuf[cell][s] = h;
                int tt = dir ? (slen[s] - 1 - t) : t;
                if (tt >= 0 && ((smask[s] >> tt) & 1)) mreg[p] = fmaxf(mreg[p], h);
            }
        }
        __syncthreads();
    }
    if (tid < NGATE) {
#pragma unroll
        for (int p = 0; p < 2; ++p) {
            int s = sb + 4 * p;
            float m = mreg[p];
            if (dir && (smask[s] >> slen[s])) m = fmaxf(m, 0.f);
            if (m == NEGV) m = 0.f;
            out[(size_t)(grp * NSEQ + s) * 968 + 868 + dir * CD_ + cell] = m;
        }
    }
}

extern "C" void kernel_launch(void* const* d_in, const int* in_sizes, int n_in,
                              void* d_out, int out_size, void* d_ws, size_t ws_size,
                              hipStream_t stream) {
    const float* bert       = (const float*)d_in[0];
    const int*   p2w        = (const int*)d_in[1];
    const int*   word_ids   = (const int*)d_in[2];
    const int*   char_ids   = (const int*)d_in[3];
    const int*   char_count = (const int*)d_in[4];
    const int*   tok_mask   = (const int*)d_in[5];
    const float* word_table = (const float*)d_in[6];
    const float* char_table = (const float*)d_in[7];
    const float* w_ih_f = (const float*)d_in[8];
    const float* w_hh_f = (const float*)d_in[9];
    const float* b_f    = (const float*)d_in[10];
    const float* w_ih_b = (const float*)d_in[11];
    const float* w_hh_b = (const float*)d_in[12];
    const float* b_b    = (const float*)d_in[13];

    float*    out   = (float*)d_out;
    unsigned* wsmin = (unsigned*)d_ws;
    float*    G     = (float*)((char*)d_ws + 256);

    hipMemsetAsync(d_ws, 0xFF, 4, stream);                       // init min slot
    kmin  <<<960, 256, 0, stream>>>(bert, wsmin);
    kword4<<<256, 256, 0, stream>>>(bert, p2w, word_ids, word_table, wsmin, out);
    if (ws_size >= WS_NEED) {
        kxg <<<2048, 256, 0, stream>>>(char_ids, char_count, char_table,
                                       w_ih_f, b_f, w_ih_b, b_b, G);
        krec<<<512, 256, 0, stream>>>(G, char_count, tok_mask, w_hh_f, w_hh_b, out);
    } else {
        klstm<<<256, 256, 0, stream>>>(char_ids, char_count, tok_mask, char_table,
                                       w_ih_f, w_hh_f, b_f, w_ih_b, w_hh_b, b_b, out);
    }
}

// Round 4
// 87.615 us; speedup vs baseline: 1.6307x; 1.6307x over previous
//
#include <hip/hip_runtime.h>
#include <hip/hip_bf16.h>

// Problem constants
#define B_   8
#define L_   128
#define S_   160
#define H_   768
#define T_   16
#define CD_  50
#define WD_  100
#define NGATE 200   // 4*CD
#define NEGV (-1e30f)

#define G_ELEMS ((size_t)2048 * T_ * NGATE)          // 6.55M floats = 26.2 MB
#define WS_NEED (256 + G_ELEMS * 4)

// ---- float <-> monotonic unsigned encoding (for atomic min on floats) ----
__device__ __forceinline__ unsigned fenc(float f) {
    unsigned b = __float_as_uint(f);
    return (b & 0x80000000u) ? ~b : (b | 0x80000000u);
}
__device__ __forceinline__ float fdec(unsigned u) {
    return __uint_as_float((u & 0x80000000u) ? (u ^ 0x80000000u) : ~u);
}

__device__ __forceinline__ float sigm(float x) {
    return __fdividef(1.f, 1.f + __expf(-x));
}
__device__ __forceinline__ float tanh_fast(float x) {
    float a = fabsf(x);
    float e = __expf(-2.f * a);
    float t = __fdividef(1.f - e, 1.f + e);
    return copysignf(t, x);
}

// ---------------- Kernel 1: global min of bert_emb ----------------
__global__ __launch_bounds__(256) void kmin(const float* __restrict__ x, unsigned* __restrict__ wsmin) {
    int i = blockIdx.x * 256 + threadIdx.x;
    const float4* x4 = (const float4*)x;
    float4 v = x4[i];
    float m = fminf(fminf(v.x, v.y), fminf(v.z, v.w));
    __shared__ float red[256];
    red[threadIdx.x] = m;
    __syncthreads();
    for (int o = 128; o > 0; o >>= 1) {
        if (threadIdx.x < o) red[threadIdx.x] = fminf(red[threadIdx.x], red[threadIdx.x + o]);
        __syncthreads();
    }
    if (threadIdx.x == 0) atomicMin(wsmin, fenc(red[0]));
}

// ---------------- Kernel 2: word_reps maxpool via compacted active-s list ----------------
// 1024 blocks (one word each), 256 threads, 3 columns/thread, i-loop unrolled x4.
__global__ __launch_bounds__(256) void kword(const float* __restrict__ bert, const int* __restrict__ p2w,
                                             const int* __restrict__ word_ids, const float* __restrict__ word_table,
                                             const unsigned* __restrict__ wsmin, float* __restrict__ out) {
    int bl = blockIdx.x;          // b*128 + l
    int b = bl >> 7;
    int l = bl & 127;
    int tid = threadIdx.x;

    __shared__ int list[S_ + 4];
    __shared__ int cnt;
    if (tid == 0) cnt = 0;
    __syncthreads();
    if (tid < S_) {
        if (p2w[bl * S_ + tid]) {
            int p = atomicAdd(&cnt, 1);    // order-independent: fmax is exact-commutative
            list[p] = tid;
        }
    }
    __syncthreads();
    int n = cnt;

    float minv = fdec(wsmin[0]);
    float a0 = minv, a1 = minv, a2 = minv;

    if (n > 0) {                            // n is block-uniform
        if (tid < ((4 - (n & 3)) & 3)) list[n + tid] = list[0];   // pad (idempotent under fmax)
        __syncthreads();
        int n4 = (n + 3) & ~3;
        const float* bb = bert + (size_t)b * S_ * H_ + tid;
        for (int i = 0; i < n4; i += 4) {
            int s0 = list[i], s1 = list[i + 1], s2 = list[i + 2], s3 = list[i + 3];
            const float* r0 = bb + (size_t)s0 * H_;
            const float* r1 = bb + (size_t)s1 * H_;
            const float* r2 = bb + (size_t)s2 * H_;
            const float* r3 = bb + (size_t)s3 * H_;
            float v00 = r0[0],   v10 = r1[0],   v20 = r2[0],   v30 = r3[0];
            float v01 = r0[256], v11 = r1[256], v21 = r2[256], v31 = r3[256];
            float v02 = r0[512], v12 = r1[512], v22 = r2[512], v32 = r3[512];
            a0 = fmaxf(a0, fmaxf(fmaxf(v00, v10), fmaxf(v20, v30)));
            a1 = fmaxf(a1, fmaxf(fmaxf(v01, v11), fmaxf(v21, v31)));
            a2 = fmaxf(a2, fmaxf(fmaxf(v02, v12), fmaxf(v22, v32)));
        }
    }
    float* orow = out + (size_t)bl * 968;
    orow[tid] = a0; orow[tid + 256] = a1; orow[tid + 512] = a2;

    if (tid < WD_) {
        int wid = word_ids[bl];
        orow[768 + tid] = word_table[(size_t)wid * WD_ + tid];
    }
    if (l == 0) {   // cls embedding = bert_emb[b,0,:]
        const float* c = bert + (size_t)b * S_ * H_;
        float* co = out + (size_t)B_ * L_ * 968 + (size_t)b * H_;
        co[tid] = c[tid]; co[tid + 256] = c[tid + 256]; co[tid + 512] = c[tid + 512];
    }
}

// ---- weight row -> 13 named float4 registers (rows are only 8B-aligned -> float2 loads) ----
#define LDW(W, p) { float2 a_ = *(const float2*)(p); float2 b_ = *(const float2*)((p) + 2); \
                    W = make_float4(a_.x, a_.y, b_.x, b_.y); }

// ---------------- Kernel 3a: x-part gates, G[n][t][j] = w_ih[j].x[n][t] + b[j] ----------------
__global__ __launch_bounds__(256) void kxg(const int* __restrict__ char_ids, const int* __restrict__ char_count,
                                           const float* __restrict__ char_table,
                                           const float* __restrict__ w_ih_f, const float* __restrict__ b_f,
                                           const float* __restrict__ w_ih_b, const float* __restrict__ b_b,
                                           float* __restrict__ G) {
    int n = blockIdx.x;
    int dir = n >> 10;
    int seq = n & 1023;
    int tid = threadIdx.x;

    __shared__ int cid[T_];
    __shared__ int len_s;
    __shared__ __align__(16) float xs[T_][52];   // padded to 52 for float4 reads; pad zeroed

    if (tid < T_) cid[tid] = char_ids[seq * T_ + tid];
    if (tid == 0) { int c = char_count[seq]; len_s = (c > 0) ? c : 1; }
    __syncthreads();
    int len = len_s;
    for (int idx = tid; idx < T_ * 52; idx += 256) {
        int t = idx / 52, k = idx % 52;
        int st = dir ? (len - 1 - t) : t;
        float xv = 0.f;
        if (k < CD_ && st >= 0) xv = char_table[cid[st] * CD_ + k];
        xs[t][k] = xv;
    }

    float4 wq0, wq1, wq2, wq3, wq4, wq5, wq6, wq7, wq8, wq9, wq10, wq11, wq12;
    float bj = 0.f;
    if (tid < NGATE) {
        const float* wrow = (dir ? w_ih_b : w_ih_f) + tid * CD_;
        LDW(wq0,  wrow +  0) LDW(wq1,  wrow +  4) LDW(wq2,  wrow +  8) LDW(wq3,  wrow + 12)
        LDW(wq4,  wrow + 16) LDW(wq5,  wrow + 20) LDW(wq6,  wrow + 24) LDW(wq7,  wrow + 28)
        LDW(wq8,  wrow + 32) LDW(wq9,  wrow + 36) LDW(wq10, wrow + 40) LDW(wq11, wrow + 44)
        { float2 a_ = *(const float2*)(wrow + 48); wq12 = make_float4(a_.x, a_.y, 0.f, 0.f); }
        bj = (dir ? b_b : b_f)[tid];
    }
    __syncthreads();

#define KXG4(i) { \
    float4 xa = *(const float4*)(x0 + 4 * i); \
    float4 xb = *(const float4*)(x1 + 4 * i); \
    accA = fmaf(wq##i.x, xa.x, accA); accA = fmaf(wq##i.y, xa.y, accA); \
    accA = fmaf(wq##i.z, xa.z, accA); accA = fmaf(wq##i.w, xa.w, accA); \
    accB = fmaf(wq##i.x, xb.x, accB); accB = fmaf(wq##i.y, xb.y, accB); \
    accB = fmaf(wq##i.z, xb.z, accB); accB = fmaf(wq##i.w, xb.w, accB); }

    if (tid < NGATE) {
        float* gout = G + (size_t)n * T_ * NGATE + tid;
#pragma unroll
        for (int t2 = 0; t2 < T_; t2 += 2) {
            const float* x0 = &xs[t2][0];
            const float* x1 = &xs[t2 + 1][0];
            float accA = bj, accB = bj;
            KXG4(0) KXG4(1) KXG4(2) KXG4(3) KXG4(4) KXG4(5) KXG4(6)
            KXG4(7) KXG4(8) KXG4(9) KXG4(10) KXG4(11) KXG4(12)
            gout[t2 * NGATE] = accA;
            gout[(t2 + 1) * NGATE] = accB;
        }
    }
}

// ---------------- Kernel 3b: recurrent h-part + fused masked max-pool ----------------
__global__ __launch_bounds__(256) void krec(const float* __restrict__ G, const int* __restrict__ char_count,
                                            const int* __restrict__ tok_mask,
                                            const float* __restrict__ w_hh_f, const float* __restrict__ w_hh_b,
                                            float* __restrict__ out) {
    int dir = blockIdx.x >> 8;
    int grp = blockIdx.x & 255;
    int tid = threadIdx.x;

    __shared__ __align__(16) float hbuf[52][4];   // [k][s], rows 50/51 stay zero
    __shared__ float gbuf[4][NGATE];
    __shared__ int slen[4], smask[4];

    if (tid < 4) {
        int n = grp * 4 + tid;
        int c = char_count[n];
        slen[tid] = (c > 0) ? c : 1;
        int mb = 0;
        for (int t = 0; t < T_; ++t) mb |= (tok_mask[n * T_ + t] != 0) << t;
        smask[tid] = mb;
    }
    for (int idx = tid; idx < 52 * 4; idx += 256) ((float*)hbuf)[idx] = 0.f;

    float4 wq0, wq1, wq2, wq3, wq4, wq5, wq6, wq7, wq8, wq9, wq10, wq11, wq12;
    float gx0 = 0.f, gx1 = 0.f, gx2 = 0.f, gx3 = 0.f;
    const float* Gb = G + (size_t)(dir * 1024 + grp * 4) * T_ * NGATE + tid;
    if (tid < NGATE) {
        const float* wrow = (dir ? w_hh_b : w_hh_f) + tid * CD_;
        LDW(wq0,  wrow +  0) LDW(wq1,  wrow +  4) LDW(wq2,  wrow +  8) LDW(wq3,  wrow + 12)
        LDW(wq4,  wrow + 16) LDW(wq5,  wrow + 20) LDW(wq6,  wrow + 24) LDW(wq7,  wrow + 28)
        LDW(wq8,  wrow + 32) LDW(wq9,  wrow + 36) LDW(wq10, wrow + 40) LDW(wq11, wrow + 44)
        { float2 a_ = *(const float2*)(wrow + 48); wq12 = make_float4(a_.x, a_.y, 0.f, 0.f); }
        gx0 = Gb[0];
        gx1 = Gb[1 * T_ * NGATE];
        gx2 = Gb[2 * T_ * NGATE];
        gx3 = Gb[3 * T_ * NGATE];
    }
    __syncthreads();

    int cell = tid % CD_;
    int sb = tid / CD_;          // 0..3
    float creg = 0.f, mreg = NEGV;

#define KREC4(i) { \
    float4 h0 = *(const float4*)&hbuf[4 * i][0]; \
    float4 h1 = *(const float4*)&hbuf[4 * i + 1][0]; \
    float4 h2 = *(const float4*)&hbuf[4 * i + 2][0]; \
    float4 h3 = *(const float4*)&hbuf[4 * i + 3][0]; \
    acc0 = fmaf(wq##i.x, h0.x, acc0); acc1 = fmaf(wq##i.x, h0.y, acc1); \
    acc2 = fmaf(wq##i.x, h0.z, acc2); acc3 = fmaf(wq##i.x, h0.w, acc3); \
    acc0 = fmaf(wq##i.y, h1.x, acc0); acc1 = fmaf(wq##i.y, h1.y, acc1); \
    acc2 = fmaf(wq##i.y, h1.z, acc2); acc3 = fmaf(wq##i.y, h1.w, acc3); \
    acc0 = fmaf(wq##i.z, h2.x, acc0); acc1 = fmaf(wq##i.z, h2.y, acc1); \
    acc2 = fmaf(wq##i.z, h2.z, acc2); acc3 = fmaf(wq##i.z, h2.w, acc3); \
    acc0 = fmaf(wq##i.w, h3.x, acc0); acc1 = fmaf(wq##i.w, h3.y, acc1); \
    acc2 = fmaf(wq##i.w, h3.z, acc2); acc3 = fmaf(wq##i.w, h3.w, acc3); }

#pragma unroll 1
    for (int t = 0; t < T_; ++t) {
        float gn0, gn1, gn2, gn3;
        if (tid < NGATE) {
            if (t < T_ - 1) {          // prefetch next step's x-gates (hidden under h-dot)
                const float* Gn = Gb + (t + 1) * NGATE;
                gn0 = Gn[0];
                gn1 = Gn[1 * T_ * NGATE];
                gn2 = Gn[2 * T_ * NGATE];
                gn3 = Gn[3 * T_ * NGATE];
            }
            float acc0 = gx0, acc1 = gx1, acc2 = gx2, acc3 = gx3;
            KREC4(0) KREC4(1) KREC4(2) KREC4(3) KREC4(4) KREC4(5) KREC4(6)
            KREC4(7) KREC4(8) KREC4(9) KREC4(10) KREC4(11) KREC4(12)
            gbuf[0][tid] = acc0; gbuf[1][tid] = acc1; gbuf[2][tid] = acc2; gbuf[3][tid] = acc3;
        }
        __syncthreads();
        if (tid < NGATE) {
            float gi = gbuf[sb][cell];
            float gf = gbuf[sb][cell + CD_];
            float gg = gbuf[sb][cell + 2 * CD_];
            float go = gbuf[sb][cell + 3 * CD_];
            float cc = sigm(gf) * creg + sigm(gi) * tanh_fast(gg);
            float h = sigm(go) * tanh_fast(cc);
            creg = cc;
            hbuf[cell][sb] = h;
            int tt = dir ? (slen[sb] - 1 - t) : t;
            if (tt >= 0 && ((smask[sb] >> tt) & 1)) mreg = fmaxf(mreg, h);
            if (t < T_ - 1) { gx0 = gn0; gx1 = gn1; gx2 = gn2; gx3 = gn3; }
        }
        __syncthreads();
    }

    if (tid < NGATE) {
        float m = mreg;
        if (dir && (smask[sb] >> slen[sb])) m = fmaxf(m, 0.f);   // masked t>=len contribute 0 in bwd half
        if (m == NEGV) m = 0.f;
        out[(size_t)(grp * 4 + sb) * 968 + 868 + dir * CD_ + cell] = m;
    }
}

// ---------------- Fallback (R2 klstm) if workspace can't hold G ----------------
#define NSEQ 8
__global__ __launch_bounds__(256, 1) void klstm(const int* __restrict__ char_ids, const int* __restrict__ char_count,
                                                const int* __restrict__ tok_mask, const float* __restrict__ char_table,
                                                const float* __restrict__ w_ih_f, const float* __restrict__ w_hh_f,
                                                const float* __restrict__ b_f,
                                                const float* __restrict__ w_ih_b, const float* __restrict__ w_hh_b,
                                                const float* __restrict__ b_b,
                                                float* __restrict__ out) {
    int dir = blockIdx.x & 1;
    int grp = blockIdx.x >> 1;
    int tid = threadIdx.x;

    __shared__ __align__(16) float xall[T_][CD_][NSEQ];
    __shared__ __align__(16) float hbuf[CD_][NSEQ];
    __shared__ __align__(16) float gbuf[NSEQ][NGATE];
    __shared__ int cid[NSEQ][T_];
    __shared__ int slen[NSEQ];
    __shared__ int smask[NSEQ];

    for (int idx = tid; idx < NSEQ * T_; idx += 256) {
        int s = idx >> 4, t = idx & 15;
        cid[s][t] = char_ids[(grp * NSEQ + s) * T_ + t];
    }
    if (tid < NSEQ) {
        int n = grp * NSEQ + tid;
        int c = char_count[n];
        slen[tid] = (c > 0) ? c : 1;
        int mb = 0;
        for (int t = 0; t < T_; ++t) mb |= (tok_mask[n * T_ + t] != 0) << t;
        smask[tid] = mb;
    }
    __syncthreads();
    for (int idx = tid; idx < T_ * CD_ * NSEQ; idx += 256) {
        int s = idx & 7;
        int k = (idx >> 3) % CD_;
        int t = idx / (CD_ * NSEQ);
        int st = dir ? (slen[s] - 1 - t) : t;
        float xv = 0.f;
        if (st >= 0) xv = char_table[cid[s][st] * CD_ + k];
        xall[t][k][s] = xv;
    }
    for (int idx = tid; idx < CD_ * NSEQ; idx += 256) hbuf[idx >> 3][idx & 7] = 0.f;

    float wihr[CD_], whhr[CD_];
    float bj = 0.f;
    if (tid < NGATE) {
        const float* wih = dir ? w_ih_b : w_ih_f;
        const float* whh = dir ? w_hh_b : w_hh_f;
#pragma unroll
        for (int k2 = 0; k2 < CD_ / 2; ++k2) {
            float2 a = *(const float2*)(wih + tid * CD_ + 2 * k2);
            wihr[2 * k2] = a.x; wihr[2 * k2 + 1] = a.y;
            float2 b2 = *(const float2*)(whh + tid * CD_ + 2 * k2);
            whhr[2 * k2] = b2.x; whhr[2 * k2 + 1] = b2.y;
        }
        bj = (dir ? b_b : b_f)[tid];
    }
    __syncthreads();

    int cell = tid % CD_;
    int sb = tid / CD_;
    float creg[2] = {0.f, 0.f};
    float mreg[2] = {NEGV, NEGV};

#pragma unroll 1
    for (int t = 0; t < T_; ++t) {
        if (tid < NGATE) {
            float acc[NSEQ];
#pragma unroll
            for (int s = 0; s < NSEQ; ++s) acc[s] = bj;
            const float* xk = &xall[t][0][0];
#pragma unroll
            for (int k = 0; k < CD_; ++k) {
                float4 xa = *(const float4*)(xk + k * NSEQ);
                float4 xb = *(const float4*)(xk + k * NSEQ + 4);
                float w = wihr[k];
                acc[0] = fmaf(w, xa.x, acc[0]); acc[1] = fmaf(w, xa.y, acc[1]);
                acc[2] = fmaf(w, xa.z, acc[2]); acc[3] = fmaf(w, xa.w, acc[3]);
                acc[4] = fmaf(w, xb.x, acc[4]); acc[5] = fmaf(w, xb.y, acc[5]);
                acc[6] = fmaf(w, xb.z, acc[6]); acc[7] = fmaf(w, xb.w, acc[7]);
            }
#pragma unroll
            for (int k = 0; k < CD_; ++k) {
                float4 ha = *(const float4*)(&hbuf[k][0]);
                float4 hb = *(const float4*)(&hbuf[k][4]);
                float w = whhr[k];
                acc[0] = fmaf(w, ha.x, acc[0]); acc[1] = fmaf(w, ha.y, acc[1]);
                acc[2] = fmaf(w, ha.z, acc[2]); acc[3] = fmaf(w, ha.w, acc[3]);
                acc[4] = fmaf(w, hb.x, acc[4]); acc[5] = fmaf(w, hb.y, acc[5]);
                acc[6] = fmaf(w, hb.z, acc[6]); acc[7] = fmaf(w, hb.w, acc[7]);
            }
#pragma unroll
            for (int s = 0; s < NSEQ; ++s) gbuf[s][tid] = acc[s];
        }
        __syncthreads();
        if (tid < NGATE) {
#pragma unroll
            for (int p = 0; p < 2; ++p) {
                int s = sb + 4 * p;
                float gi = gbuf[s][cell];
                float gf = gbuf[s][cell + CD_];
                float gg = gbuf[s][cell + 2 * CD_];
                float go = gbuf[s][cell + 3 * CD_];
                float cc = creg[p];
                cc = sigm(gf) * cc + sigm(gi) * tanh_fast(gg);
                float h = sigm(go) * tanh_fast(cc);
                creg[p] = cc;
                hbuf[cell][s] = h;
                int tt = dir ? (slen[s] - 1 - t) : t;
                if (tt >= 0 && ((smask[s] >> tt) & 1)) mreg[p] = fmaxf(mreg[p], h);
            }
        }
        __syncthreads();
    }
    if (tid < NGATE) {
#pragma unroll
        for (int p = 0; p < 2; ++p) {
            int s = sb + 4 * p;
            float m = mreg[p];
            if (dir && (smask[s] >> slen[s])) m = fmaxf(m, 0.f);
            if (m == NEGV) m = 0.f;
            out[(size_t)(grp * NSEQ + s) * 968 + 868 + dir * CD_ + cell] = m;
        }
    }
}

extern "C" void kernel_launch(void* const* d_in, const int* in_sizes, int n_in,
                              void* d_out, int out_size, void* d_ws, size_t ws_size,
                              hipStream_t stream) {
    const float* bert       = (const float*)d_in[0];
    const int*   p2w        = (const int*)d_in[1];
    const int*   word_ids   = (const int*)d_in[2];
    const int*   char_ids   = (const int*)d_in[3];
    const int*   char_count = (const int*)d_in[4];
    const int*   tok_mask   = (const int*)d_in[5];
    const float* word_table = (const float*)d_in[6];
    const float* char_table = (const float*)d_in[7];
    const float* w_ih_f = (const float*)d_in[8];
    const float* w_hh_f = (const float*)d_in[9];
    const float* b_f    = (const float*)d_in[10];
    const float* w_ih_b = (const float*)d_in[11];
    const float* w_hh_b = (const float*)d_in[12];
    const float* b_b    = (const float*)d_in[13];

    float*    out   = (float*)d_out;
    unsigned* wsmin = (unsigned*)d_ws;
    float*    G     = (float*)((char*)d_ws + 256);

    hipMemsetAsync(d_ws, 0xFF, 4, stream);                       // init min slot
    kmin  <<<960, 256, 0, stream>>>(bert, wsmin);
    kword <<<B_ * L_, 256, 0, stream>>>(bert, p2w, word_ids, word_table, wsmin, out);
    if (ws_size >= WS_NEED) {
        kxg <<<2048, 256, 0, stream>>>(char_ids, char_count, char_table,
                                       w_ih_f, b_f, w_ih_b, b_b, G);
        krec<<<512, 256, 0, stream>>>(G, char_count, tok_mask, w_hh_f, w_hh_b, out);
    } else {
        klstm<<<256, 256, 0, stream>>>(char_ids, char_count, tok_mask, char_table,
                                       w_ih_f, w_hh_f, b_f, w_ih_b, w_hh_b, b_b, out);
    }
}

// Round 5
// 76.390 us; speedup vs baseline: 1.8704x; 1.1469x over previous
//
#include <hip/hip_runtime.h>
#include <hip/hip_bf16.h>

// Problem constants
#define B_   8
#define L_   128
#define S_   160
#define H_   768
#define T_   16
#define CD_  50
#define WD_  100
#define NGATE 200   // 4*CD
#define NEGV (-1e30f)
#define FMAXV 3.402823466e+38f

// workspace layout (bytes):
//   [0..4)       final global min (float), written by kmin2
//   [256..1216)  240 partial minima (float), written by kmin1
//   [8192..)     G buffer for LSTM x-gates
#define G_OFF   8192
#define G_ELEMS ((size_t)2048 * T_ * NGATE)          // 6.55M floats = 26.2 MB
#define WS_NEED (G_OFF + G_ELEMS * 4)

__device__ __forceinline__ float sigm(float x) {
    return __fdividef(1.f, 1.f + __expf(-x));
}
__device__ __forceinline__ float tanh_fast(float x) {
    float a = fabsf(x);
    float e = __expf(-2.f * a);
    float t = __fdividef(1.f - e, 1.f + e);
    return copysignf(t, x);
}

// ---------------- Kernel 1a: per-block partial min of bert_emb ----------------
// 983040 floats = 240 blocks * 256 threads * 4 float4
__global__ __launch_bounds__(256) void kmin1(const float* __restrict__ x, float* __restrict__ pmin) {
    int tid = threadIdx.x;
    int base = blockIdx.x * 1024 + tid;          // float4 index
    const float4* x4 = (const float4*)x;
    float m = FMAXV;
#pragma unroll
    for (int i = 0; i < 4; ++i) {
        float4 v = x4[base + i * 256];
        m = fminf(m, fminf(fminf(v.x, v.y), fminf(v.z, v.w)));
    }
    __shared__ float red[256];
    red[tid] = m;
    __syncthreads();
    for (int o = 128; o > 0; o >>= 1) {
        if (tid < o) red[tid] = fminf(red[tid], red[tid + o]);
        __syncthreads();
    }
    if (tid == 0) pmin[blockIdx.x] = red[0];
}

// ---------------- Kernel 1b: reduce 240 partials -> ws[0] (plain store) ----------------
__global__ __launch_bounds__(256) void kmin2(const float* __restrict__ pmin, float* __restrict__ wsmin) {
    int tid = threadIdx.x;
    float m = (tid < 240) ? pmin[tid] : FMAXV;
    __shared__ float red[256];
    red[tid] = m;
    __syncthreads();
    for (int o = 128; o > 0; o >>= 1) {
        if (tid < o) red[tid] = fminf(red[tid], red[tid + o]);
        __syncthreads();
    }
    if (tid == 0) wsmin[0] = red[0];
}

// ---------------- Kernel 2: word_reps maxpool via compacted active-s list ----------------
// 1024 blocks (one word each), 256 threads, 3 columns/thread, i-loop unrolled x4.
__global__ __launch_bounds__(256) void kword(const float* __restrict__ bert, const int* __restrict__ p2w,
                                             const int* __restrict__ word_ids, const float* __restrict__ word_table,
                                             const float* __restrict__ wsmin, float* __restrict__ out) {
    int bl = blockIdx.x;          // b*128 + l
    int b = bl >> 7;
    int l = bl & 127;
    int tid = threadIdx.x;

    __shared__ int list[S_ + 4];
    __shared__ int cnt;
    if (tid == 0) cnt = 0;
    __syncthreads();
    if (tid < S_) {
        if (p2w[bl * S_ + tid]) {
            int p = atomicAdd(&cnt, 1);    // order-independent: fmax is exact-commutative
            list[p] = tid;
        }
    }
    __syncthreads();
    int n = cnt;

    float minv = wsmin[0];
    float a0 = minv, a1 = minv, a2 = minv;

    if (n > 0) {                            // n is block-uniform
        if (tid < ((4 - (n & 3)) & 3)) list[n + tid] = list[0];   // pad (idempotent under fmax)
        __syncthreads();
        int n4 = (n + 3) & ~3;
        const float* bb = bert + (size_t)b * S_ * H_ + tid;
        for (int i = 0; i < n4; i += 4) {
            int s0 = list[i], s1 = list[i + 1], s2 = list[i + 2], s3 = list[i + 3];
            const float* r0 = bb + (size_t)s0 * H_;
            const float* r1 = bb + (size_t)s1 * H_;
            const float* r2 = bb + (size_t)s2 * H_;
            const float* r3 = bb + (size_t)s3 * H_;
            float v00 = r0[0],   v10 = r1[0],   v20 = r2[0],   v30 = r3[0];
            float v01 = r0[256], v11 = r1[256], v21 = r2[256], v31 = r3[256];
            float v02 = r0[512], v12 = r1[512], v22 = r2[512], v32 = r3[512];
            a0 = fmaxf(a0, fmaxf(fmaxf(v00, v10), fmaxf(v20, v30)));
            a1 = fmaxf(a1, fmaxf(fmaxf(v01, v11), fmaxf(v21, v31)));
            a2 = fmaxf(a2, fmaxf(fmaxf(v02, v12), fmaxf(v22, v32)));
        }
    }
    float* orow = out + (size_t)bl * 968;
    orow[tid] = a0; orow[tid + 256] = a1; orow[tid + 512] = a2;

    if (tid < WD_) {
        int wid = word_ids[bl];
        orow[768 + tid] = word_table[(size_t)wid * WD_ + tid];
    }
    if (l == 0) {   // cls embedding = bert_emb[b,0,:]
        const float* c = bert + (size_t)b * S_ * H_;
        float* co = out + (size_t)B_ * L_ * 968 + (size_t)b * H_;
        co[tid] = c[tid]; co[tid + 256] = c[tid + 256]; co[tid + 512] = c[tid + 512];
    }
}

// ---- weight row -> 13 named float4 registers (rows are only 8B-aligned -> float2 loads) ----
#define LDW(W, p) { float2 a_ = *(const float2*)(p); float2 b_ = *(const float2*)((p) + 2); \
                    W = make_float4(a_.x, a_.y, b_.x, b_.y); }

// ---------------- Kernel 3a: x-part gates, G[n][t][j] = w_ih[j].x[n][t] + b[j] ----------------
__global__ __launch_bounds__(256) void kxg(const int* __restrict__ char_ids, const int* __restrict__ char_count,
                                           const float* __restrict__ char_table,
                                           const float* __restrict__ w_ih_f, const float* __restrict__ b_f,
                                           const float* __restrict__ w_ih_b, const float* __restrict__ b_b,
                                           float* __restrict__ G) {
    int n = blockIdx.x;
    int dir = n >> 10;
    int seq = n & 1023;
    int tid = threadIdx.x;

    __shared__ int cid[T_];
    __shared__ int len_s;
    __shared__ __align__(16) float xs[T_][52];   // padded to 52 for float4 reads; pad zeroed

    if (tid < T_) cid[tid] = char_ids[seq * T_ + tid];
    if (tid == 0) { int c = char_count[seq]; len_s = (c > 0) ? c : 1; }
    __syncthreads();
    int len = len_s;
    for (int idx = tid; idx < T_ * 52; idx += 256) {
        int t = idx / 52, k = idx % 52;
        int st = dir ? (len - 1 - t) : t;
        float xv = 0.f;
        if (k < CD_ && st >= 0) xv = char_table[cid[st] * CD_ + k];
        xs[t][k] = xv;
    }

    float4 wq0, wq1, wq2, wq3, wq4, wq5, wq6, wq7, wq8, wq9, wq10, wq11, wq12;
    float bj = 0.f;
    if (tid < NGATE) {
        const float* wrow = (dir ? w_ih_b : w_ih_f) + tid * CD_;
        LDW(wq0,  wrow +  0) LDW(wq1,  wrow +  4) LDW(wq2,  wrow +  8) LDW(wq3,  wrow + 12)
        LDW(wq4,  wrow + 16) LDW(wq5,  wrow + 20) LDW(wq6,  wrow + 24) LDW(wq7,  wrow + 28)
        LDW(wq8,  wrow + 32) LDW(wq9,  wrow + 36) LDW(wq10, wrow + 40) LDW(wq11, wrow + 44)
        { float2 a_ = *(const float2*)(wrow + 48); wq12 = make_float4(a_.x, a_.y, 0.f, 0.f); }
        bj = (dir ? b_b : b_f)[tid];
    }
    __syncthreads();

#define KXG4(i) { \
    float4 xa = *(const float4*)(x0 + 4 * i); \
    float4 xb = *(const float4*)(x1 + 4 * i); \
    accA = fmaf(wq##i.x, xa.x, accA); accA = fmaf(wq##i.y, xa.y, accA); \
    accA = fmaf(wq##i.z, xa.z, accA); accA = fmaf(wq##i.w, xa.w, accA); \
    accB = fmaf(wq##i.x, xb.x, accB); accB = fmaf(wq##i.y, xb.y, accB); \
    accB = fmaf(wq##i.z, xb.z, accB); accB = fmaf(wq##i.w, xb.w, accB); }

    if (tid < NGATE) {
        float* gout = G + (size_t)n * T_ * NGATE + tid;
#pragma unroll
        for (int t2 = 0; t2 < T_; t2 += 2) {
            const float* x0 = &xs[t2][0];
            const float* x1 = &xs[t2 + 1][0];
            float accA = bj, accB = bj;
            KXG4(0) KXG4(1) KXG4(2) KXG4(3) KXG4(4) KXG4(5) KXG4(6)
            KXG4(7) KXG4(8) KXG4(9) KXG4(10) KXG4(11) KXG4(12)
            gout[t2 * NGATE] = accA;
            gout[(t2 + 1) * NGATE] = accB;
        }
    }
}

// ---------------- Kernel 3b: recurrent h-part + fused masked max-pool ----------------
__global__ __launch_bounds__(256) void krec(const float* __restrict__ G, const int* __restrict__ char_count,
                                            const int* __restrict__ tok_mask,
                                            const float* __restrict__ w_hh_f, const float* __restrict__ w_hh_b,
                                            float* __restrict__ out) {
    int dir = blockIdx.x >> 8;
    int grp = blockIdx.x & 255;
    int tid = threadIdx.x;

    __shared__ __align__(16) float hbuf[52][4];   // [k][s], rows 50/51 stay zero
    __shared__ float gbuf[4][NGATE];
    __shared__ int slen[4], smask[4];

    if (tid < 4) {
        int n = grp * 4 + tid;
        int c = char_count[n];
        slen[tid] = (c > 0) ? c : 1;
        int mb = 0;
        for (int t = 0; t < T_; ++t) mb |= (tok_mask[n * T_ + t] != 0) << t;
        smask[tid] = mb;
    }
    for (int idx = tid; idx < 52 * 4; idx += 256) ((float*)hbuf)[idx] = 0.f;

    float4 wq0, wq1, wq2, wq3, wq4, wq5, wq6, wq7, wq8, wq9, wq10, wq11, wq12;
    float gx0 = 0.f, gx1 = 0.f, gx2 = 0.f, gx3 = 0.f;
    const float* Gb = G + (size_t)(dir * 1024 + grp * 4) * T_ * NGATE + tid;
    if (tid < NGATE) {
        const float* wrow = (dir ? w_hh_b : w_hh_f) + tid * CD_;
        LDW(wq0,  wrow +  0) LDW(wq1,  wrow +  4) LDW(wq2,  wrow +  8) LDW(wq3,  wrow + 12)
        LDW(wq4,  wrow + 16) LDW(wq5,  wrow + 20) LDW(wq6,  wrow + 24) LDW(wq7,  wrow + 28)
        LDW(wq8,  wrow + 32) LDW(wq9,  wrow + 36) LDW(wq10, wrow + 40) LDW(wq11, wrow + 44)
        { float2 a_ = *(const float2*)(wrow + 48); wq12 = make_float4(a_.x, a_.y, 0.f, 0.f); }
        gx0 = Gb[0];
        gx1 = Gb[1 * T_ * NGATE];
        gx2 = Gb[2 * T_ * NGATE];
        gx3 = Gb[3 * T_ * NGATE];
    }
    __syncthreads();

    int cell = tid % CD_;
    int sb = tid / CD_;          // 0..3
    float creg = 0.f, mreg = NEGV;

#define KREC4(i) { \
    float4 h0 = *(const float4*)&hbuf[4 * i][0]; \
    float4 h1 = *(const float4*)&hbuf[4 * i + 1][0]; \
    float4 h2 = *(const float4*)&hbuf[4 * i + 2][0]; \
    float4 h3 = *(const float4*)&hbuf[4 * i + 3][0]; \
    acc0 = fmaf(wq##i.x, h0.x, acc0); acc1 = fmaf(wq##i.x, h0.y, acc1); \
    acc2 = fmaf(wq##i.x, h0.z, acc2); acc3 = fmaf(wq##i.x, h0.w, acc3); \
    acc0 = fmaf(wq##i.y, h1.x, acc0); acc1 = fmaf(wq##i.y, h1.y, acc1); \
    acc2 = fmaf(wq##i.y, h1.z, acc2); acc3 = fmaf(wq##i.y, h1.w, acc3); \
    acc0 = fmaf(wq##i.z, h2.x, acc0); acc1 = fmaf(wq##i.z, h2.y, acc1); \
    acc2 = fmaf(wq##i.z, h2.z, acc2); acc3 = fmaf(wq##i.z, h2.w, acc3); \
    acc0 = fmaf(wq##i.w, h3.x, acc0); acc1 = fmaf(wq##i.w, h3.y, acc1); \
    acc2 = fmaf(wq##i.w, h3.z, acc2); acc3 = fmaf(wq##i.w, h3.w, acc3); }

#pragma unroll 1
    for (int t = 0; t < T_; ++t) {
        float gn0, gn1, gn2, gn3;
        if (tid < NGATE) {
            if (t < T_ - 1) {          // prefetch next step's x-gates (hidden under h-dot)
                const float* Gn = Gb + (t + 1) * NGATE;
                gn0 = Gn[0];
                gn1 = Gn[1 * T_ * NGATE];
                gn2 = Gn[2 * T_ * NGATE];
                gn3 = Gn[3 * T_ * NGATE];
            }
            float acc0 = gx0, acc1 = gx1, acc2 = gx2, acc3 = gx3;
            KREC4(0) KREC4(1) KREC4(2) KREC4(3) KREC4(4) KREC4(5) KREC4(6)
            KREC4(7) KREC4(8) KREC4(9) KREC4(10) KREC4(11) KREC4(12)
            gbuf[0][tid] = acc0; gbuf[1][tid] = acc1; gbuf[2][tid] = acc2; gbuf[3][tid] = acc3;
        }
        __syncthreads();
        if (tid < NGATE) {
            float gi = gbuf[sb][cell];
            float gf = gbuf[sb][cell + CD_];
            float gg = gbuf[sb][cell + 2 * CD_];
            float go = gbuf[sb][cell + 3 * CD_];
            float cc = sigm(gf) * creg + sigm(gi) * tanh_fast(gg);
            float h = sigm(go) * tanh_fast(cc);
            creg = cc;
            hbuf[cell][sb] = h;
            int tt = dir ? (slen[sb] - 1 - t) : t;
            if (tt >= 0 && ((smask[sb] >> tt) & 1)) mreg = fmaxf(mreg, h);
            if (t < T_ - 1) { gx0 = gn0; gx1 = gn1; gx2 = gn2; gx3 = gn3; }
        }
        __syncthreads();
    }

    if (tid < NGATE) {
        float m = mreg;
        if (dir && (smask[sb] >> slen[sb])) m = fmaxf(m, 0.f);   // masked t>=len contribute 0 in bwd half
        if (m == NEGV) m = 0.f;
        out[(size_t)(grp * 4 + sb) * 968 + 868 + dir * CD_ + cell] = m;
    }
}

// ---------------- Fallback (R2 klstm) if workspace can't hold G ----------------
#define NSEQ 8
__global__ __launch_bounds__(256, 1) void klstm(const int* __restrict__ char_ids, const int* __restrict__ char_count,
                                                const int* __restrict__ tok_mask, const float* __restrict__ char_table,
                                                const float* __restrict__ w_ih_f, const float* __restrict__ w_hh_f,
                                                const float* __restrict__ b_f,
                                                const float* __restrict__ w_ih_b, const float* __restrict__ w_hh_b,
                                                const float* __restrict__ b_b,
                                                float* __restrict__ out) {
    int dir = blockIdx.x & 1;
    int grp = blockIdx.x >> 1;
    int tid = threadIdx.x;

    __shared__ __align__(16) float xall[T_][CD_][NSEQ];
    __shared__ __align__(16) float hbuf[CD_][NSEQ];
    __shared__ __align__(16) float gbuf[NSEQ][NGATE];
    __shared__ int cid[NSEQ][T_];
    __shared__ int slen[NSEQ];
    __shared__ int smask[NSEQ];

    for (int idx = tid; idx < NSEQ * T_; idx += 256) {
        int s = idx >> 4, t = idx & 15;
        cid[s][t] = char_ids[(grp * NSEQ + s) * T_ + t];
    }
    if (tid < NSEQ) {
        int n = grp * NSEQ + tid;
        int c = char_count[n];
        slen[tid] = (c > 0) ? c : 1;
        int mb = 0;
        for (int t = 0; t < T_; ++t) mb |= (tok_mask[n * T_ + t] != 0) << t;
        smask[tid] = mb;
    }
    __syncthreads();
    for (int idx = tid; idx < T_ * CD_ * NSEQ; idx += 256) {
        int s = idx & 7;
        int k = (idx >> 3) % CD_;
        int t = idx / (CD_ * NSEQ);
        int st = dir ? (slen[s] - 1 - t) : t;
        float xv = 0.f;
        if (st >= 0) xv = char_table[cid[s][st] * CD_ + k];
        xall[t][k][s] = xv;
    }
    for (int idx = tid; idx < CD_ * NSEQ; idx += 256) hbuf[idx >> 3][idx & 7] = 0.f;

    float wihr[CD_], whhr[CD_];
    float bj = 0.f;
    if (tid < NGATE) {
        const float* wih = dir ? w_ih_b : w_ih_f;
        const float* whh = dir ? w_hh_b : w_hh_f;
#pragma unroll
        for (int k2 = 0; k2 < CD_ / 2; ++k2) {
            float2 a = *(const float2*)(wih + tid * CD_ + 2 * k2);
            wihr[2 * k2] = a.x; wihr[2 * k2 + 1] = a.y;
            float2 b2 = *(const float2*)(whh + tid * CD_ + 2 * k2);
            whhr[2 * k2] = b2.x; whhr[2 * k2 + 1] = b2.y;
        }
        bj = (dir ? b_b : b_f)[tid];
    }
    __syncthreads();

    int cell = tid % CD_;
    int sb = tid / CD_;
    float creg[2] = {0.f, 0.f};
    float mreg[2] = {NEGV, NEGV};

#pragma unroll 1
    for (int t = 0; t < T_; ++t) {
        if (tid < NGATE) {
            float acc[NSEQ];
#pragma unroll
            for (int s = 0; s < NSEQ; ++s) acc[s] = bj;
            const float* xk = &xall[t][0][0];
#pragma unroll
            for (int k = 0; k < CD_; ++k) {
                float4 xa = *(const float4*)(xk + k * NSEQ);
                float4 xb = *(const float4*)(xk + k * NSEQ + 4);
                float w = wihr[k];
                acc[0] = fmaf(w, xa.x, acc[0]); acc[1] = fmaf(w, xa.y, acc[1]);
                acc[2] = fmaf(w, xa.z, acc[2]); acc[3] = fmaf(w, xa.w, acc[3]);
                acc[4] = fmaf(w, xb.x, acc[4]); acc[5] = fmaf(w, xb.y, acc[5]);
                acc[6] = fmaf(w, xb.z, acc[6]); acc[7] = fmaf(w, xb.w, acc[7]);
            }
#pragma unroll
            for (int k = 0; k < CD_; ++k) {
                float4 ha = *(const float4*)(&hbuf[k][0]);
                float4 hb = *(const float4*)(&hbuf[k][4]);
                float w = whhr[k];
                acc[0] = fmaf(w, ha.x, acc[0]); acc[1] = fmaf(w, ha.y, acc[1]);
                acc[2] = fmaf(w, ha.z, acc[2]); acc[3] = fmaf(w, ha.w, acc[3]);
                acc[4] = fmaf(w, hb.x, acc[4]); acc[5] = fmaf(w, hb.y, acc[5]);
                acc[6] = fmaf(w, hb.z, acc[6]); acc[7] = fmaf(w, hb.w, acc[7]);
            }
#pragma unroll
            for (int s = 0; s < NSEQ; ++s) gbuf[s][tid] = acc[s];
        }
        __syncthreads();
        if (tid < NGATE) {
#pragma unroll
            for (int p = 0; p < 2; ++p) {
                int s = sb + 4 * p;
                float gi = gbuf[s][cell];
                float gf = gbuf[s][cell + CD_];
                float gg = gbuf[s][cell + 2 * CD_];
                float go = gbuf[s][cell + 3 * CD_];
                float cc = creg[p];
                cc = sigm(gf) * cc + sigm(gi) * tanh_fast(gg);
                float h = sigm(go) * tanh_fast(cc);
                creg[p] = cc;
                hbuf[cell][s] = h;
                int tt = dir ? (slen[s] - 1 - t) : t;
                if (tt >= 0 && ((smask[s] >> tt) & 1)) mreg[p] = fmaxf(mreg[p], h);
            }
        }
        __syncthreads();
    }
    if (tid < NGATE) {
#pragma unroll
        for (int p = 0; p < 2; ++p) {
            int s = sb + 4 * p;
            float m = mreg[p];
            if (dir && (smask[s] >> slen[s])) m = fmaxf(m, 0.f);
            if (m == NEGV) m = 0.f;
            out[(size_t)(grp * NSEQ + s) * 968 + 868 + dir * CD_ + cell] = m;
        }
    }
}

extern "C" void kernel_launch(void* const* d_in, const int* in_sizes, int n_in,
                              void* d_out, int out_size, void* d_ws, size_t ws_size,
                              hipStream_t stream) {
    const float* bert       = (const float*)d_in[0];
    const int*   p2w        = (const int*)d_in[1];
    const int*   word_ids   = (const int*)d_in[2];
    const int*   char_ids   = (const int*)d_in[3];
    const int*   char_count = (const int*)d_in[4];
    const int*   tok_mask   = (const int*)d_in[5];
    const float* word_table = (const float*)d_in[6];
    const float* char_table = (const float*)d_in[7];
    const float* w_ih_f = (const float*)d_in[8];
    const float* w_hh_f = (const float*)d_in[9];
    const float* b_f    = (const float*)d_in[10];
    const float* w_ih_b = (const float*)d_in[11];
    const float* w_hh_b = (const float*)d_in[12];
    const float* b_b    = (const float*)d_in[13];

    float*    out   = (float*)d_out;
    float*    wsmin = (float*)d_ws;
    float*    pmin  = (float*)((char*)d_ws + 256);
    float*    G     = (float*)((char*)d_ws + G_OFF);

    kmin1<<<240, 256, 0, stream>>>(bert, pmin);
    kmin2<<<1,   256, 0, stream>>>(pmin, wsmin);
    kword<<<B_ * L_, 256, 0, stream>>>(bert, p2w, word_ids, word_table, wsmin, out);
    if (ws_size >= WS_NEED) {
        kxg <<<2048, 256, 0, stream>>>(char_ids, char_count, char_table,
                                       w_ih_f, b_f, w_ih_b, b_b, G);
        krec<<<512, 256, 0, stream>>>(G, char_count, tok_mask, w_hh_f, w_hh_b, out);
    } else {
        klstm<<<256, 256, 0, stream>>>(char_ids, char_count, tok_mask, char_table,
                                       w_ih_f, w_hh_f, b_f, w_ih_b, w_hh_b, b_b, out);
    }
}

// Round 6
// 75.212 us; speedup vs baseline: 1.8997x; 1.0157x over previous
//
#include <hip/hip_runtime.h>
#include <hip/hip_bf16.h>

// Problem constants
#define B_   8
#define L_   128
#define S_   160
#define H_   768
#define T_   16
#define CD_  50
#define WD_  100
#define NGATE 200   // 4*CD
#define NEGV (-1e30f)
#define FMAXV 3.402823466e+38f
#define NELEM (B_ * S_ * H_)      // 983040 floats in bert_emb

__device__ __forceinline__ float sigm(float x) {
    return __fdividef(1.f, 1.f + __expf(-x));
}
__device__ __forceinline__ float tanh_fast(float x) {
    float a = fabsf(x);
    float e = __expf(-2.f * a);
    float t = __fdividef(1.f - e, 1.f + e);
    return copysignf(t, x);
}

// shared-memory overlays (union via raw buffer; role is block-uniform)
struct WordS {
    int list[S_ + 4];
    int cnt;
    float red[256];
};
struct LstmS {
    float xs[T_][52][4];    // [t][k][s], k 50..51 zero pad
    float hbuf[52][4];      // [k][s], rows 50/51 stay zero
    float gbuf[4][NGATE];
    int cid[4][T_];
    int slen[4];
    int smask[4];
};
#define SMEM_BYTES 17664      // >= max(sizeof(WordS)=1684, sizeof(LstmS)=17632)

// ---- weight row -> 13 named float4 registers (rows are 8B-aligned -> float2 loads) ----
#define LDW(W, p) { float2 a_ = *(const float2*)(p); float2 b_ = *(const float2*)((p) + 2); \
                    W = make_float4(a_.x, a_.y, b_.x, b_.y); }
#define LDW2(W, p) { float2 a_ = *(const float2*)(p); W = make_float4(a_.x, a_.y, 0.f, 0.f); }

// dot-product macro: acc0..3 += w.{xyzw} * v[k][s], v = float[*][4] base vk (floats)
#define DOT4(W, vk, i) { \
    const float4 vA = *(const float4*)((vk) + 16 * i + 0); \
    const float4 vB = *(const float4*)((vk) + 16 * i + 4); \
    const float4 vC = *(const float4*)((vk) + 16 * i + 8); \
    const float4 vD = *(const float4*)((vk) + 16 * i + 12); \
    acc0 = fmaf(W##i.x, vA.x, acc0); acc1 = fmaf(W##i.x, vA.y, acc1); \
    acc2 = fmaf(W##i.x, vA.z, acc2); acc3 = fmaf(W##i.x, vA.w, acc3); \
    acc0 = fmaf(W##i.y, vB.x, acc0); acc1 = fmaf(W##i.y, vB.y, acc1); \
    acc2 = fmaf(W##i.y, vB.z, acc2); acc3 = fmaf(W##i.y, vB.w, acc3); \
    acc0 = fmaf(W##i.z, vC.x, acc0); acc1 = fmaf(W##i.z, vC.y, acc1); \
    acc2 = fmaf(W##i.z, vC.z, acc2); acc3 = fmaf(W##i.z, vC.w, acc3); \
    acc0 = fmaf(W##i.w, vD.x, acc0); acc1 = fmaf(W##i.w, vD.y, acc1); \
    acc2 = fmaf(W##i.w, vD.z, acc2); acc3 = fmaf(W##i.w, vD.w, acc3); }

// ---------------- word_reps maxpool + word_embed + cls (one word per call) ----------------
__device__ void kword_body(int bl, char* smem, const float* __restrict__ bert,
                           const int* __restrict__ p2w, const int* __restrict__ word_ids,
                           const float* __restrict__ word_table, float* __restrict__ out) {
    WordS& sh = *(WordS*)smem;
    int b = bl >> 7;
    int l = bl & 127;
    int tid = threadIdx.x;

    if (tid == 0) sh.cnt = 0;
    __syncthreads();
    if (tid < S_) {
        if (p2w[bl * S_ + tid]) {
            int p = atomicAdd(&sh.cnt, 1);   // order-independent: fmax is exact-commutative
            sh.list[p] = tid;
        }
    }
    __syncthreads();
    int n = sh.cnt;

    float a0, a1, a2;
    if (n > 0) {                             // n is block-uniform
        a0 = a1 = a2 = -FMAXV;
        if (tid < ((4 - (n & 3)) & 3)) sh.list[n + tid] = sh.list[0];   // pad (idempotent)
        __syncthreads();
        int n4 = (n + 3) & ~3;
        const float* bb = bert + (size_t)b * S_ * H_ + tid;
        for (int i = 0; i < n4; i += 4) {
            int s0 = sh.list[i], s1 = sh.list[i + 1], s2 = sh.list[i + 2], s3 = sh.list[i + 3];
            const float* r0 = bb + (size_t)s0 * H_;
            const float* r1 = bb + (size_t)s1 * H_;
            const float* r2 = bb + (size_t)s2 * H_;
            const float* r3 = bb + (size_t)s3 * H_;
            float v00 = r0[0],   v10 = r1[0],   v20 = r2[0],   v30 = r3[0];
            float v01 = r0[256], v11 = r1[256], v21 = r2[256], v31 = r3[256];
            float v02 = r0[512], v12 = r1[512], v22 = r2[512], v32 = r3[512];
            a0 = fmaxf(a0, fmaxf(fmaxf(v00, v10), fmaxf(v20, v30)));
            a1 = fmaxf(a1, fmaxf(fmaxf(v01, v11), fmaxf(v21, v31)));
            a2 = fmaxf(a2, fmaxf(fmaxf(v02, v12), fmaxf(v22, v32)));
        }
    } else {
        // all-masked word (probability ~2^-160; kept for strict correctness):
        // result = global min of bert_emb, computed locally.
        float m = FMAXV;
        const float4* x4 = (const float4*)bert;
        for (int i = tid; i < NELEM / 4; i += 256) {
            float4 v = x4[i];
            m = fminf(m, fminf(fminf(v.x, v.y), fminf(v.z, v.w)));
        }
        sh.red[tid] = m;
        __syncthreads();
        for (int o = 128; o > 0; o >>= 1) {
            if (tid < o) sh.red[tid] = fminf(sh.red[tid], sh.red[tid + o]);
            __syncthreads();
        }
        a0 = a1 = a2 = sh.red[0];
    }

    float* orow = out + (size_t)bl * 968;
    orow[tid] = a0; orow[tid + 256] = a1; orow[tid + 512] = a2;

    if (tid < WD_) {
        int wid = word_ids[bl];
        orow[768 + tid] = word_table[(size_t)wid * WD_ + tid];
    }
    if (l == 0) {   // cls embedding = bert_emb[b,0,:]
        const float* c = bert + (size_t)b * S_ * H_;
        float* co = out + (size_t)B_ * L_ * 968 + (size_t)b * H_;
        co[tid] = c[tid]; co[tid + 256] = c[tid + 256]; co[tid + 512] = c[tid + 512];
    }
}

// ---------------- fused BiLSTM unit: x-gates in-loop + recurrence + masked max-pool ----------------
// unit = dir*256 + grp; block owns 4 sequences of one direction for all 16 steps.
__device__ void lstm_body(int unit, char* smem,
                          const int* __restrict__ char_ids, const int* __restrict__ char_count,
                          const int* __restrict__ tok_mask, const float* __restrict__ char_table,
                          const float* __restrict__ w_ih_f, const float* __restrict__ w_hh_f,
                          const float* __restrict__ b_f,
                          const float* __restrict__ w_ih_b, const float* __restrict__ w_hh_b,
                          const float* __restrict__ b_b,
                          float* __restrict__ out) {
    LstmS& sh = *(LstmS*)smem;
    int dir = unit >> 8;
    int grp = unit & 255;
    int tid = threadIdx.x;

    if (tid < 64) {
        int s = tid >> 4, t = tid & 15;
        sh.cid[s][t] = char_ids[(grp * 4 + s) * T_ + t];
    }
    if (tid >= 64 && tid < 68) {
        int s = tid - 64;
        int n = grp * 4 + s;
        int c = char_count[n];
        sh.slen[s] = (c > 0) ? c : 1;
        int mb = 0;
        for (int t = 0; t < T_; ++t) mb |= (tok_mask[n * T_ + t] != 0) << t;
        sh.smask[s] = mb;
    }
    if (tid >= 68 && tid < 68 + 52 * 4 / 2) {   // zero hbuf (104 threads x 2 floats)
        int i = (tid - 68) * 2;
        ((float*)sh.hbuf)[i] = 0.f;
        ((float*)sh.hbuf)[i + 1] = 0.f;
    }
    __syncthreads();   // slen/cid ready

    // stage x for all timesteps, [t][k][s] layout (reversed + zero-padded for backward)
    for (int idx = tid; idx < T_ * 52 * 4; idx += 256) {
        int s = idx & 3;
        int k = (idx >> 2) % 52;
        int t = idx / (52 * 4);
        int st = dir ? (sh.slen[s] - 1 - t) : t;
        float v = 0.f;
        if (k < CD_ && st >= 0) v = char_table[sh.cid[s][st] * CD_ + k];
        sh.xs[t][k][s] = v;
    }

    // weight rows resident in named registers: 13 float4 each for w_ih[j], w_hh[j]
    float4 ih0, ih1, ih2, ih3, ih4, ih5, ih6, ih7, ih8, ih9, ih10, ih11, ih12;
    float4 hh0, hh1, hh2, hh3, hh4, hh5, hh6, hh7, hh8, hh9, hh10, hh11, hh12;
    float bj = 0.f;
    if (tid < NGATE) {
        const float* wi = (dir ? w_ih_b : w_ih_f) + tid * CD_;
        const float* wh = (dir ? w_hh_b : w_hh_f) + tid * CD_;
        LDW(ih0,  wi +  0) LDW(ih1,  wi +  4) LDW(ih2,  wi +  8) LDW(ih3,  wi + 12)
        LDW(ih4,  wi + 16) LDW(ih5,  wi + 20) LDW(ih6,  wi + 24) LDW(ih7,  wi + 28)
        LDW(ih8,  wi + 32) LDW(ih9,  wi + 36) LDW(ih10, wi + 40) LDW(ih11, wi + 44)
        LDW2(ih12, wi + 48)
        LDW(hh0,  wh +  0) LDW(hh1,  wh +  4) LDW(hh2,  wh +  8) LDW(hh3,  wh + 12)
        LDW(hh4,  wh + 16) LDW(hh5,  wh + 20) LDW(hh6,  wh + 24) LDW(hh7,  wh + 28)
        LDW(hh8,  wh + 32) LDW(hh9,  wh + 36) LDW(hh10, wh + 40) LDW(hh11, wh + 44)
        LDW2(hh12, wh + 48)
        bj = (dir ? b_b : b_f)[tid];
    }
    __syncthreads();   // xs staged

    int cell = tid % CD_;
    int sb = tid / CD_;          // 0..3 for active threads
    float creg = 0.f, mreg = NEGV;

#pragma unroll 1
    for (int t = 0; t < T_; ++t) {
        if (tid < NGATE) {
            float acc0 = bj, acc1 = bj, acc2 = bj, acc3 = bj;
            const float* xk = &sh.xs[t][0][0];
            DOT4(ih, xk, 0) DOT4(ih, xk, 1) DOT4(ih, xk, 2) DOT4(ih, xk, 3)
            DOT4(ih, xk, 4) DOT4(ih, xk, 5) DOT4(ih, xk, 6) DOT4(ih, xk, 7)
            DOT4(ih, xk, 8) DOT4(ih, xk, 9) DOT4(ih, xk, 10) DOT4(ih, xk, 11)
            DOT4(ih, xk, 12)
            const float* hk = &sh.hbuf[0][0];
            DOT4(hh, hk, 0) DOT4(hh, hk, 1) DOT4(hh, hk, 2) DOT4(hh, hk, 3)
            DOT4(hh, hk, 4) DOT4(hh, hk, 5) DOT4(hh, hk, 6) DOT4(hh, hk, 7)
            DOT4(hh, hk, 8) DOT4(hh, hk, 9) DOT4(hh, hk, 10) DOT4(hh, hk, 11)
            DOT4(hh, hk, 12)
            sh.gbuf[0][tid] = acc0; sh.gbuf[1][tid] = acc1;
            sh.gbuf[2][tid] = acc2; sh.gbuf[3][tid] = acc3;
        }
        __syncthreads();
        if (tid < NGATE) {
            float gi = sh.gbuf[sb][cell];
            float gf = sh.gbuf[sb][cell + CD_];
            float gg = sh.gbuf[sb][cell + 2 * CD_];
            float go = sh.gbuf[sb][cell + 3 * CD_];
            float cc = sigm(gf) * creg + sigm(gi) * tanh_fast(gg);
            float h = sigm(go) * tanh_fast(cc);
            creg = cc;
            sh.hbuf[cell][sb] = h;
            int tt = dir ? (sh.slen[sb] - 1 - t) : t;   // position in original time order
            if (tt >= 0 && ((sh.smask[sb] >> tt) & 1)) mreg = fmaxf(mreg, h);
        }
        __syncthreads();
    }

    if (tid < NGATE) {
        float m = mreg;
        // backward half: masked positions at t >= len contribute h_bwd = 0
        if (dir && (sh.smask[sb] >> sh.slen[sb])) m = fmaxf(m, 0.f);
        if (m == NEGV) m = 0.f;
        out[(size_t)(grp * 4 + sb) * 968 + 868 + dir * CD_ + cell] = m;
    }
}

// ---------------- mega kernel: interleaved roles, one dispatch ----------------
// 1536 blocks: bid%3 in {0,1} -> kword (word = (bid/3)*2 + bid%3), bid%3==2 -> lstm unit bid/3.
__global__ __launch_bounds__(256, 2) void kmega(
        const float* __restrict__ bert, const int* __restrict__ p2w,
        const int* __restrict__ word_ids, const int* __restrict__ char_ids,
        const int* __restrict__ char_count, const int* __restrict__ tok_mask,
        const float* __restrict__ word_table, const float* __restrict__ char_table,
        const float* __restrict__ w_ih_f, const float* __restrict__ w_hh_f,
        const float* __restrict__ b_f,
        const float* __restrict__ w_ih_b, const float* __restrict__ w_hh_b,
        const float* __restrict__ b_b,
        float* __restrict__ out) {
    __shared__ __align__(16) char smem[SMEM_BYTES];
    int bid = blockIdx.x;
    int role = bid % 3;
    int unit = bid / 3;
    if (role < 2) {
        kword_body(unit * 2 + role, smem, bert, p2w, word_ids, word_table, out);
    } else {
        lstm_body(unit, smem, char_ids, char_count, tok_mask, char_table,
                  w_ih_f, w_hh_f, b_f, w_ih_b, w_hh_b, b_b, out);
    }
}

extern "C" void kernel_launch(void* const* d_in, const int* in_sizes, int n_in,
                              void* d_out, int out_size, void* d_ws, size_t ws_size,
                              hipStream_t stream) {
    const float* bert       = (const float*)d_in[0];
    const int*   p2w        = (const int*)d_in[1];
    const int*   word_ids   = (const int*)d_in[2];
    const int*   char_ids   = (const int*)d_in[3];
    const int*   char_count = (const int*)d_in[4];
    const int*   tok_mask   = (const int*)d_in[5];
    const float* word_table = (const float*)d_in[6];
    const float* char_table = (const float*)d_in[7];
    const float* w_ih_f = (const float*)d_in[8];
    const float* w_hh_f = (const float*)d_in[9];
    const float* b_f    = (const float*)d_in[10];
    const float* w_ih_b = (const float*)d_in[11];
    const float* w_hh_b = (const float*)d_in[12];
    const float* b_b    = (const float*)d_in[13];

    float* out = (float*)d_out;

    kmega<<<1536, 256, 0, stream>>>(bert, p2w, word_ids, char_ids, char_count, tok_mask,
                                    word_table, char_table,
                                    w_ih_f, w_hh_f, b_f, w_ih_b, w_hh_b, b_b, out);
}